// Round 3
// baseline (52.384 us; speedup 1.0000x reference)
//
#include <hip/hip_runtime.h>
#include <stdint.h>

#define NB   8
#define INC  64
#define INN  20000
#define OUTC 64
#define OUTN 8000
#define MAXD 32

// ---------- helpers ----------
__device__ __forceinline__ uint32_t pack_bf16_2(float a, float b) {
    uint32_t ua = __float_as_uint(a);
    uint32_t ub = __float_as_uint(b);
    uint32_t ra = (ua + 0x7FFFu + ((ua >> 16) & 1u)) >> 16;   // RTNE
    uint32_t rb = (ub + 0x7FFFu + ((ub >> 16) & 1u)) >> 16;
    return (ra & 0xFFFFu) | (rb << 16);
}

// ---------- kernel 0: pack A as u16-pair planes, per-o scale, W^T ----------
__global__ void prep_kernel(const int* __restrict__ A, const float* __restrict__ mask,
                            const float* __restrict__ ct_v, const float* __restrict__ ct_g,
                            uint4* __restrict__ AQ, float2* __restrict__ scale2,
                            float* __restrict__ W_T) {
    if (blockIdx.x == 64) {
        int k = threadIdx.x;
        if (k < OUTC) {
            float s = 0.f;
            for (int c = 0; c < INC; ++c) { float v = ct_v[k * INC + c]; s += v * v; }
            float inv = ct_g[k] / sqrtf(s);
            for (int c = 0; c < INC; ++c) W_T[c * OUTC + k] = ct_v[k * INC + c] * inv;
        }
        return;
    }
    int o = blockIdx.x * 128 + threadIdx.x;
    if (o >= OUTN) return;
    const int4* arow = (const int4*)(A + (size_t)o * MAXD);
#pragma unroll
    for (int j = 0; j < 4; ++j) {
        int4 v0 = arow[2 * j];
        int4 v1 = arow[2 * j + 1];
        uint4 pk;   // 8 u16 indices per uint4 plane element
        pk.x = (uint32_t)v0.x | ((uint32_t)v0.y << 16);
        pk.y = (uint32_t)v0.z | ((uint32_t)v0.w << 16);
        pk.z = (uint32_t)v1.x | ((uint32_t)v1.y << 16);
        pk.w = (uint32_t)v1.z | ((uint32_t)v1.w << 16);
        AQ[(size_t)j * OUTN + o] = pk;
    }
    float invdeg = mask[(size_t)o * MAXD];          // mask[o][0] = 1/deg (deg>=8)
    float deg    = rintf(1.0f / invdeg);
    scale2[o] = make_float2(invdeg, 32.0f - deg);
}

// ---------- kernel 1: fused xw-staging (2ch bf16 in u32) + gather-pool ----------
__global__ __launch_bounds__(1024, 8)
void gather_kernel(const float* __restrict__ x, const float* __restrict__ w,
                   const uint4* __restrict__ AQ, const float2* __restrict__ scale2,
                   float* __restrict__ pooled) {
    __shared__ __align__(16) uint32_t smem[INN];   // 80,000 B -> 2 blocks/CU
    int h = blockIdx.x;          // 0..1  (o-range half)
    int g = blockIdx.y;          // 0..31 (channel pair)
    int b = blockIdx.z;          // 0..7
    int tid = threadIdx.x;
    int c0 = g * 2;

    // ---- stage: xw = x*w for channels c0,c0+1, pack 2xbf16 per inn-elem ----
    const float* xb = x + ((size_t)b * INC + c0) * INN;
    const float* wb = w + (size_t)c0 * INN;
    for (int p = tid; p < INN / 4; p += 1024) {      // 5000 float4 positions
        int i = p * 4;
        float4 x0 = *(const float4*)(xb + i);
        float4 x1 = *(const float4*)(xb + INN + i);
        float4 w0 = *(const float4*)(wb + i);
        float4 w1 = *(const float4*)(wb + INN + i);
        uint4 pk;
        pk.x = pack_bf16_2(x0.x * w0.x, x1.x * w1.x);
        pk.y = pack_bf16_2(x0.y * w0.y, x1.y * w1.y);
        pk.z = pack_bf16_2(x0.z * w0.z, x1.z * w1.z);
        pk.w = pack_bf16_2(x0.w * w0.w, x1.w * w1.w);
        *(uint4*)&smem[i] = pk;
    }
    __syncthreads();

    // correction values (xw[c][0]) — broadcast read
    uint32_t z = smem[0];
    float z0 = __uint_as_float(z << 16);
    float z1 = __uint_as_float(z & 0xFFFF0000u);

    const char* sbase = (const char*)smem;
    int obase = h * (OUTN / 2);
    int oend  = obase + (OUTN / 2);
#pragma unroll
    for (int it = 0; it < 4; ++it) {
        int o = obase + tid + it * 1024;
        if (o < oend) {
            uint32_t q[16];
#pragma unroll
            for (int j = 0; j < 4; ++j) {
                uint4 v = AQ[(size_t)j * OUTN + o];
                q[j * 4 + 0] = v.x; q[j * 4 + 1] = v.y;
                q[j * 4 + 2] = v.z; q[j * 4 + 3] = v.w;
            }
            float a0 = 0.f, a1 = 0.f;
#pragma unroll
            for (int p = 0; p < 16; ++p) {
                uint32_t u   = q[p];
                int off0 = (int)(u & 0xFFFFu) << 2;
                int off1 = (int)(u >> 16) << 2;
                uint32_t v0 = *(const uint32_t*)(sbase + off0);
                uint32_t v1 = *(const uint32_t*)(sbase + off1);
                a0 += __uint_as_float(v0 << 16);
                a1 += __uint_as_float(v0 & 0xFFFF0000u);
                a0 += __uint_as_float(v1 << 16);
                a1 += __uint_as_float(v1 & 0xFFFF0000u);
            }
            float2 sc = scale2[o];   // {1/deg, 32-deg}
            a0 = (a0 - sc.y * z0) * sc.x;
            a1 = (a1 - sc.y * z1) * sc.x;
            pooled[((size_t)(b * OUTC + c0 + 0)) * OUTN + o] = a0;
            pooled[((size_t)(b * OUTC + c0 + 1)) * OUTN + o] = a1;
        }
    }
}

// ---------- kernel 2: y = W @ pooled + bias (in place over d_out) ----------
__global__ __launch_bounds__(256)
void out_kernel(float* io, const float* __restrict__ W_T,
                const float* __restrict__ bias) {
    __shared__ __align__(16) float sp[INC][128];
    __shared__ __align__(16) float sw[INC][OUTC];
    int obase = blockIdx.x * 128;
    int b     = blockIdx.y;

    const float* pb = io + (size_t)b * INC * OUTN;
    for (int idx = threadIdx.x; idx < INC * 32; idx += 256) {   // 2048 float4
        int c  = idx >> 5;
        int q  = idx & 31;
        int o4 = obase + q * 4;
        float4 v = (o4 < OUTN) ? *(const float4*)(pb + (size_t)c * OUTN + o4)
                               : make_float4(0.f, 0.f, 0.f, 0.f);
        *(float4*)(&sp[c][q * 4]) = v;
    }
    for (int idx = threadIdx.x; idx < (INC * OUTC) / 4; idx += 256) { // 1024 float4
        ((float4*)sw)[idx] = ((const float4*)W_T)[idx];
    }
    __syncthreads();

    int t   = threadIdx.x;
    int kt  = t >> 4;            // 0..15
    int ot0 = (t & 15) * 8;      // 0..120
    int k0  = kt * 4;

    float acc[4][8];
#pragma unroll
    for (int kk = 0; kk < 4; ++kk) {
#pragma unroll
        for (int jh = 0; jh < 2; ++jh) {
            int o4 = obase + ot0 + jh * 4;
            float4 bv = (o4 < OUTN)
                ? *(const float4*)(bias + (size_t)(k0 + kk) * OUTN + o4)
                : make_float4(0.f, 0.f, 0.f, 0.f);
            acc[kk][jh * 4 + 0] = bv.x;
            acc[kk][jh * 4 + 1] = bv.y;
            acc[kk][jh * 4 + 2] = bv.z;
            acc[kk][jh * 4 + 3] = bv.w;
        }
    }

#pragma unroll 4
    for (int c = 0; c < INC; ++c) {
        float4 w4  = *(const float4*)(&sw[c][k0]);
        float4 pa  = *(const float4*)(&sp[c][ot0]);
        float4 pb4 = *(const float4*)(&sp[c][ot0 + 4]);
        float p[8] = {pa.x, pa.y, pa.z, pa.w, pb4.x, pb4.y, pb4.z, pb4.w};
        float wv[4] = {w4.x, w4.y, w4.z, w4.w};
#pragma unroll
        for (int kk = 0; kk < 4; ++kk)
#pragma unroll
            for (int j = 0; j < 8; ++j)
                acc[kk][j] += wv[kk] * p[j];
    }

    int o0 = obase + ot0;
    if (o0 < OUTN) {    // OUTN % 8 == 0 -> whole 8 valid
#pragma unroll
        for (int kk = 0; kk < 4; ++kk) {
            float4 s0 = make_float4(acc[kk][0], acc[kk][1], acc[kk][2], acc[kk][3]);
            float4 s1 = make_float4(acc[kk][4], acc[kk][5], acc[kk][6], acc[kk][7]);
            float* dst = io + ((size_t)(b * OUTC + k0 + kk)) * OUTN + o0;
            *(float4*)(dst)     = s0;
            *(float4*)(dst + 4) = s1;
        }
    }
}

// ---------- launch ----------
extern "C" void kernel_launch(void* const* d_in, const int* in_sizes, int n_in,
                              void* d_out, int out_size, void* d_ws, size_t ws_size,
                              hipStream_t stream) {
    const float* x    = (const float*)d_in[0];
    const float* w    = (const float*)d_in[1];
    const float* ct_v = (const float*)d_in[2];
    const float* ct_g = (const float*)d_in[3];
    const float* bias = (const float*)d_in[4];
    const float* mask = (const float*)d_in[5];
    const int*   A    = (const int*)d_in[6];
    float* y = (float*)d_out;

    char* ws = (char*)d_ws;
    uint4*  AQ     = (uint4*)(ws);                    // 4*8000*16 = 512,000 B
    float2* scale2 = (float2*)(ws + 512000);          // 8000*8    =  64,000 B
    float*  W_T    = (float*)(ws + 576000);           // 64*64*4   =  16,384 B

    prep_kernel<<<65, 128, 0, stream>>>(A, mask, ct_v, ct_g, AQ, scale2, W_T);
    gather_kernel<<<dim3(2, 32, NB), 1024, 0, stream>>>(x, w, AQ, scale2, y);
    out_kernel<<<dim3(63, NB), 256, 0, stream>>>(y, W_T, bias);
}

// Round 4
// 51.052 us; speedup vs baseline: 1.0261x; 1.0261x over previous
//
#include <hip/hip_runtime.h>
#include <stdint.h>

#define NB   8
#define INC  64
#define INN  20000
#define OUTC 64
#define OUTN 8000
#define MAXD 32
#define NG   16   // groups of 4 input channels

// ---------- helpers ----------
__device__ __forceinline__ uint32_t pack_bf16_2(float a, float b) {
    uint32_t ua = __float_as_uint(a);
    uint32_t ub = __float_as_uint(b);
    uint32_t ra = (ua + 0x7FFFu + ((ua >> 16) & 1u)) >> 16;   // RTNE
    uint32_t rb = (ub + 0x7FFFu + ((ub >> 16) & 1u)) >> 16;
    return (ra & 0xFFFFu) | (rb << 16);
}

// ---------- kernel 0: pack A as u16 (idx<<1) planes, per-o scale, W^T ----------
__global__ void prep_kernel(const int* __restrict__ A, const float* __restrict__ mask,
                            const float* __restrict__ ct_v, const float* __restrict__ ct_g,
                            uint4* __restrict__ AQ, float2* __restrict__ scale2,
                            float* __restrict__ W_T) {
    if (blockIdx.x == 64) {
        int k = threadIdx.x;
        if (k < OUTC) {
            float s = 0.f;
            for (int c = 0; c < INC; ++c) { float v = ct_v[k * INC + c]; s += v * v; }
            float inv = ct_g[k] / sqrtf(s);
            for (int c = 0; c < INC; ++c) W_T[c * OUTC + k] = ct_v[k * INC + c] * inv;
        }
        return;
    }
    int o = blockIdx.x * 128 + threadIdx.x;
    if (o >= OUTN) return;
    const int4* arow = (const int4*)(A + (size_t)o * MAXD);
#pragma unroll
    for (int j = 0; j < 4; ++j) {
        int4 v0 = arow[2 * j];
        int4 v1 = arow[2 * j + 1];
        uint4 pk;   // 8 u16 (idx<<1) per plane element; (idx<<1) < 40000 fits u16
        pk.x = (uint32_t)(v0.x << 1) | ((uint32_t)(v0.y << 1) << 16);
        pk.y = (uint32_t)(v0.z << 1) | ((uint32_t)(v0.w << 1) << 16);
        pk.z = (uint32_t)(v1.x << 1) | ((uint32_t)(v1.y << 1) << 16);
        pk.w = (uint32_t)(v1.z << 1) | ((uint32_t)(v1.w << 1) << 16);
        AQ[(size_t)j * OUTN + o] = pk;
    }
    float invdeg = mask[(size_t)o * MAXD];          // mask[o][0] = 1/deg (deg>=8)
    float deg    = rintf(1.0f / invdeg);
    scale2[o] = make_float2(invdeg, 32.0f - deg);
}

// ---------- kernel 1: xw = x*weight, packed 4 channels of bf16 ----------
__global__ __launch_bounds__(256)
void xw_kernel(const float* __restrict__ x, const float* __restrict__ w,
               uint2* __restrict__ xwi) {
    int t    = threadIdx.x;
    int tile = blockIdx.x;          // 0..19
    int g    = blockIdx.y;          // 0..15
    int b    = blockIdx.z;          // 0..7
    int i0   = tile * 1024 + t * 4;
    if (i0 >= INN) return;
    float4 p[4];
#pragma unroll
    for (int cl = 0; cl < 4; ++cl) {
        int c = g * 4 + cl;
        float4 xv = *(const float4*)(x + ((size_t)(b * INC + c)) * INN + i0);
        float4 wv = *(const float4*)(w + (size_t)c * INN + i0);
        p[cl] = make_float4(xv.x * wv.x, xv.y * wv.y, xv.z * wv.z, xv.w * wv.w);
    }
    uint4 o01, o23;
    o01.x = pack_bf16_2(p[0].x, p[1].x);  o01.y = pack_bf16_2(p[2].x, p[3].x);
    o01.z = pack_bf16_2(p[0].y, p[1].y);  o01.w = pack_bf16_2(p[2].y, p[3].y);
    o23.x = pack_bf16_2(p[0].z, p[1].z);  o23.y = pack_bf16_2(p[2].z, p[3].z);
    o23.z = pack_bf16_2(p[0].w, p[1].w);  o23.w = pack_bf16_2(p[2].w, p[3].w);
    uint2* dst = xwi + ((size_t)(b * NG + g)) * INN + i0;
    ((uint4*)dst)[0] = o01;
    ((uint4*)dst)[1] = o23;
}

// ---------- kernel 2: DMA-staged gather-pool (4ch per ds_read_b64) ----------
__global__ __launch_bounds__(1024, 4)
void gather_kernel(const uint2* __restrict__ xwi, const uint4* __restrict__ AQ,
                   const float2* __restrict__ scale2, float* __restrict__ pooled) {
    __shared__ __align__(16) uint2 smem[INN];   // 160,000 B
    int h = blockIdx.x;          // 0..1  (o-range half)
    int g = blockIdx.y;          // 0..15
    int b = blockIdx.z;          // 0..7
    int tid = threadIdx.x;
    int c0 = g * 4;

    // ---- stage via async global->LDS DMA (width 16) ----
    const uint4* src = (const uint4*)(xwi + ((size_t)(b * NG + g)) * INN);  // 10000 x 16B
#pragma unroll
    for (int k = 0; k < 10; ++k) {
        int i = tid + k * 1024;
        if (i < INN / 2) {
            __builtin_amdgcn_global_load_lds(
                (const __attribute__((address_space(1))) uint32_t*)(src + i),
                (__attribute__((address_space(3))) uint32_t*)((char*)smem + ((i & ~63) * 16)),
                16, 0, 0);
        }
    }

    // ---- prefetch first o-batch indices while DMA is in flight ----
    int obase = h * (OUTN / 2);
    int oend  = obase + (OUTN / 2);
    int o0 = obase + tid;                     // tid < 1024 < 4000 -> valid
    uint4 q0 = AQ[o0];
    uint4 q1 = AQ[OUTN + o0];
    uint4 q2 = AQ[2 * OUTN + o0];
    uint4 q3 = AQ[3 * OUTN + o0];

    __syncthreads();   // drains vmcnt (DMA + index loads)

    uint2 z = smem[0];
    float z0 = __uint_as_float(z.x << 16);
    float z1 = __uint_as_float(z.x & 0xFFFF0000u);
    float z2 = __uint_as_float(z.y << 16);
    float z3 = __uint_as_float(z.y & 0xFFFF0000u);

    const char* sb = (const char*)smem;

#pragma unroll
    for (int it = 0; it < 4; ++it) {
        int o = obase + tid + it * 1024;
        // 2-deep prefetch of next batch
        uint4 n0 = q0, n1 = q1, n2 = q2, n3 = q3;
        if (it < 3) {
            int op = o + 1024; if (op >= oend) op = oend - 1;
            n0 = AQ[op];
            n1 = AQ[OUTN + op];
            n2 = AQ[2 * OUTN + op];
            n3 = AQ[3 * OUTN + op];
        }
        if (o < oend) {
            float a0 = 0.f, a1 = 0.f, a2 = 0.f, a3 = 0.f;
#define DO_U32(u)                                                      \
            {                                                          \
                uint32_t off0 = (u & 0xFFFFu) << 2;                    \
                uint32_t off1 = (u >> 16) << 2;                        \
                uint2 v0 = *(const uint2*)(sb + off0);                 \
                uint2 v1 = *(const uint2*)(sb + off1);                 \
                a0 += __uint_as_float(v0.x << 16);                     \
                a1 += __uint_as_float(v0.x & 0xFFFF0000u);             \
                a2 += __uint_as_float(v0.y << 16);                     \
                a3 += __uint_as_float(v0.y & 0xFFFF0000u);             \
                a0 += __uint_as_float(v1.x << 16);                     \
                a1 += __uint_as_float(v1.x & 0xFFFF0000u);             \
                a2 += __uint_as_float(v1.y << 16);                     \
                a3 += __uint_as_float(v1.y & 0xFFFF0000u);             \
            }
            DO_U32(q0.x) DO_U32(q0.y) DO_U32(q0.z) DO_U32(q0.w)
            DO_U32(q1.x) DO_U32(q1.y) DO_U32(q1.z) DO_U32(q1.w)
            DO_U32(q2.x) DO_U32(q2.y) DO_U32(q2.z) DO_U32(q2.w)
            DO_U32(q3.x) DO_U32(q3.y) DO_U32(q3.z) DO_U32(q3.w)
#undef DO_U32
            float2 sc = scale2[o];   // {1/deg, 32-deg}
            a0 = (a0 - sc.y * z0) * sc.x;
            a1 = (a1 - sc.y * z1) * sc.x;
            a2 = (a2 - sc.y * z2) * sc.x;
            a3 = (a3 - sc.y * z3) * sc.x;
            pooled[((size_t)(b * OUTC + c0 + 0)) * OUTN + o] = a0;
            pooled[((size_t)(b * OUTC + c0 + 1)) * OUTN + o] = a1;
            pooled[((size_t)(b * OUTC + c0 + 2)) * OUTN + o] = a2;
            pooled[((size_t)(b * OUTC + c0 + 3)) * OUTN + o] = a3;
        }
        q0 = n0; q1 = n1; q2 = n2; q3 = n3;
    }
}

// ---------- kernel 3: y = W @ pooled + bias (in place over d_out) ----------
__global__ __launch_bounds__(256)
void out_kernel(float* io, const float* __restrict__ W_T,
                const float* __restrict__ bias) {
    __shared__ __align__(16) float sp[INC][128];
    __shared__ __align__(16) float sw[INC][OUTC];
    int obase = blockIdx.x * 128;
    int b     = blockIdx.y;

    const float* pb = io + (size_t)b * INC * OUTN;
    for (int idx = threadIdx.x; idx < INC * 32; idx += 256) {   // 2048 float4
        int c  = idx >> 5;
        int q  = idx & 31;
        int o4 = obase + q * 4;
        float4 v = (o4 < OUTN) ? *(const float4*)(pb + (size_t)c * OUTN + o4)
                               : make_float4(0.f, 0.f, 0.f, 0.f);
        *(float4*)(&sp[c][q * 4]) = v;
    }
    for (int idx = threadIdx.x; idx < (INC * OUTC) / 4; idx += 256) { // 1024 float4
        ((float4*)sw)[idx] = ((const float4*)W_T)[idx];
    }
    __syncthreads();

    int t   = threadIdx.x;
    int kt  = t >> 4;            // 0..15
    int ot0 = (t & 15) * 8;      // 0..120
    int k0  = kt * 4;

    float acc[4][8];
#pragma unroll
    for (int kk = 0; kk < 4; ++kk) {
#pragma unroll
        for (int jh = 0; jh < 2; ++jh) {
            int o4 = obase + ot0 + jh * 4;
            float4 bv = (o4 < OUTN)
                ? *(const float4*)(bias + (size_t)(k0 + kk) * OUTN + o4)
                : make_float4(0.f, 0.f, 0.f, 0.f);
            acc[kk][jh * 4 + 0] = bv.x;
            acc[kk][jh * 4 + 1] = bv.y;
            acc[kk][jh * 4 + 2] = bv.z;
            acc[kk][jh * 4 + 3] = bv.w;
        }
    }

#pragma unroll 4
    for (int c = 0; c < INC; ++c) {
        float4 w4  = *(const float4*)(&sw[c][k0]);
        float4 pa  = *(const float4*)(&sp[c][ot0]);
        float4 pb4 = *(const float4*)(&sp[c][ot0 + 4]);
        float p[8] = {pa.x, pa.y, pa.z, pa.w, pb4.x, pb4.y, pb4.z, pb4.w};
        float wv[4] = {w4.x, w4.y, w4.z, w4.w};
#pragma unroll
        for (int kk = 0; kk < 4; ++kk)
#pragma unroll
            for (int j = 0; j < 8; ++j)
                acc[kk][j] += wv[kk] * p[j];
    }

    int o0 = obase + ot0;
    if (o0 < OUTN) {    // OUTN % 8 == 0 -> whole 8 valid
#pragma unroll
        for (int kk = 0; kk < 4; ++kk) {
            float4 s0 = make_float4(acc[kk][0], acc[kk][1], acc[kk][2], acc[kk][3]);
            float4 s1 = make_float4(acc[kk][4], acc[kk][5], acc[kk][6], acc[kk][7]);
            float* dst = io + ((size_t)(b * OUTC + k0 + kk)) * OUTN + o0;
            *(float4*)(dst)     = s0;
            *(float4*)(dst + 4) = s1;
        }
    }
}

// ---------- launch ----------
extern "C" void kernel_launch(void* const* d_in, const int* in_sizes, int n_in,
                              void* d_out, int out_size, void* d_ws, size_t ws_size,
                              hipStream_t stream) {
    const float* x    = (const float*)d_in[0];
    const float* w    = (const float*)d_in[1];
    const float* ct_v = (const float*)d_in[2];
    const float* ct_g = (const float*)d_in[3];
    const float* bias = (const float*)d_in[4];
    const float* mask = (const float*)d_in[5];
    const int*   A    = (const int*)d_in[6];
    float* y = (float*)d_out;

    char* ws = (char*)d_ws;
    uint2*  xwi    = (uint2*)(ws);                    // 8*16*20000*8 = 20,480,000 B
    uint4*  AQ     = (uint4*)(ws + 20480000);         // 4*8000*16    =    512,000 B
    float2* scale2 = (float2*)(ws + 20992000);        // 8000*8       =     64,000 B
    float*  W_T    = (float*)(ws + 21056000);         // 64*64*4      =     16,384 B

    xw_kernel<<<dim3(20, NG, NB), 256, 0, stream>>>(x, w, xwi);
    prep_kernel<<<65, 128, 0, stream>>>(A, mask, ct_v, ct_g, AQ, scale2, W_T);
    gather_kernel<<<dim3(2, NG, NB), 1024, 0, stream>>>(xwi, AQ, scale2, y);
    out_kernel<<<dim3(63, NB), 256, 0, stream>>>(y, W_T, bias);
}

// Round 5
// 49.128 us; speedup vs baseline: 1.0663x; 1.0392x over previous
//
#include <hip/hip_runtime.h>
#include <stdint.h>

#define NB   8
#define INC  64
#define INN  20000
#define OUTC 64
#define OUTN 8000
#define MAXD 32

typedef float f32x2 __attribute__((ext_vector_type(2)));

// ---------- kernel 0: pack A as u16 (idx<<1) planes, per-o scale, W^T ----------
__global__ void prep_kernel(const int* __restrict__ A, const float* __restrict__ mask,
                            const float* __restrict__ ct_v, const float* __restrict__ ct_g,
                            uint4* __restrict__ AQ, float2* __restrict__ scale2,
                            float* __restrict__ W_T) {
    if (blockIdx.x == 64) {
        int k = threadIdx.x;
        if (k < OUTC) {
            float s = 0.f;
            for (int c = 0; c < INC; ++c) { float v = ct_v[k * INC + c]; s += v * v; }
            float inv = ct_g[k] / sqrtf(s);
            for (int c = 0; c < INC; ++c) W_T[c * OUTC + k] = ct_v[k * INC + c] * inv;
        }
        return;
    }
    int o = blockIdx.x * 128 + threadIdx.x;
    if (o >= OUTN) return;
    const int4* arow = (const int4*)(A + (size_t)o * MAXD);
#pragma unroll
    for (int j = 0; j < 4; ++j) {
        int4 v0 = arow[2 * j];
        int4 v1 = arow[2 * j + 1];
        uint4 pk;   // 8 u16 (idx<<1) per plane element; (idx<<1) < 40000 fits u16
        pk.x = (uint32_t)(v0.x << 1) | ((uint32_t)(v0.y << 1) << 16);
        pk.y = (uint32_t)(v0.z << 1) | ((uint32_t)(v0.w << 1) << 16);
        pk.z = (uint32_t)(v1.x << 1) | ((uint32_t)(v1.y << 1) << 16);
        pk.w = (uint32_t)(v1.z << 1) | ((uint32_t)(v1.w << 1) << 16);
        AQ[(size_t)j * OUTN + o] = pk;
    }
    float invdeg = mask[(size_t)o * MAXD];          // mask[o][0] = 1/deg (deg>=8)
    float deg    = rintf(1.0f / invdeg);
    // fold the 1/256 fp8 pre-scale into the final scale
    scale2[o] = make_float2(invdeg * (1.0f / 256.0f), 32.0f - deg);
}

// ---------- kernel 1: xw = x*weight*256, packed 8 channels of fp8 e4m3 ----------
__global__ __launch_bounds__(256)
void xw_kernel(const float* __restrict__ x, const float* __restrict__ w,
               uint2* __restrict__ xwi) {
    int t    = threadIdx.x;
    int tile = blockIdx.x;          // 0..39
    int g8   = blockIdx.y;          // 0..7
    int b    = blockIdx.z;          // 0..7
    int i0   = (tile * 256 + t) * 2;
    if (i0 >= INN) return;
    int c0 = g8 * 8;
    const float* xb = x + ((size_t)b * INC + c0) * INN + i0;
    const float* wb = w + (size_t)c0 * INN + i0;
    float p0[8], p1[8];
#pragma unroll
    for (int cl = 0; cl < 8; ++cl) {
        float2 xv = *(const float2*)(xb + (size_t)cl * INN);
        float2 wv = *(const float2*)(wb + (size_t)cl * INN);
        p0[cl] = xv.x * wv.x * 256.0f;
        p1[cl] = xv.y * wv.y * 256.0f;
    }
    uint32_t a0, a1, b0, b1;
    a0 = __builtin_amdgcn_cvt_pk_fp8_f32(p0[0], p0[1], 0,  false);
    a0 = __builtin_amdgcn_cvt_pk_fp8_f32(p0[2], p0[3], a0, true);
    a1 = __builtin_amdgcn_cvt_pk_fp8_f32(p0[4], p0[5], 0,  false);
    a1 = __builtin_amdgcn_cvt_pk_fp8_f32(p0[6], p0[7], a1, true);
    b0 = __builtin_amdgcn_cvt_pk_fp8_f32(p1[0], p1[1], 0,  false);
    b0 = __builtin_amdgcn_cvt_pk_fp8_f32(p1[2], p1[3], b0, true);
    b1 = __builtin_amdgcn_cvt_pk_fp8_f32(p1[4], p1[5], 0,  false);
    b1 = __builtin_amdgcn_cvt_pk_fp8_f32(p1[6], p1[7], b1, true);
    uint4 out = make_uint4(a0, a1, b0, b1);   // elem i0: (a0,a1), elem i0+1: (b0,b1)
    *(uint4*)(xwi + ((size_t)(b * 8 + g8)) * INN + i0) = out;
}

// ---------- kernel 2: DMA-staged gather-pool (8ch fp8 per ds_read_b64) ----------
__global__ __launch_bounds__(1024, 4)
void gather_kernel(const uint2* __restrict__ xwi, const uint4* __restrict__ AQ,
                   const float2* __restrict__ scale2, float* __restrict__ pooled) {
    __shared__ __align__(16) uint2 smem[INN];   // 160,000 B
    int s  = blockIdx.x;         // 0..3  (o-quarter)
    int g8 = blockIdx.y;         // 0..7
    int b  = blockIdx.z;         // 0..7
    int tid = threadIdx.x;
    int c0 = g8 * 8;

    // ---- stage via async global->LDS DMA (width 16) ----
    const uint4* src = (const uint4*)(xwi + ((size_t)(b * 8 + g8)) * INN);  // 10000 x 16B
#pragma unroll
    for (int k = 0; k < 10; ++k) {
        int i = tid + k * 1024;
        if (i < INN / 2) {
            __builtin_amdgcn_global_load_lds(
                (const __attribute__((address_space(1))) uint32_t*)(src + i),
                (__attribute__((address_space(3))) uint32_t*)((char*)smem + ((i & ~63) * 16)),
                16, 0, 0);
        }
    }

    // ---- prefetch first o-batch indices while DMA is in flight ----
    int obase = s * (OUTN / 4);
    int oend  = obase + (OUTN / 4);
    int o0 = obase + tid;                     // tid < 1024 < 2000 -> valid
    uint4 q0 = AQ[o0];
    uint4 q1 = AQ[OUTN + o0];
    uint4 q2 = AQ[2 * OUTN + o0];
    uint4 q3 = AQ[3 * OUTN + o0];

    __syncthreads();   // drains vmcnt (DMA + index loads)

    // correction values xw_s[0] for the 8 channels
    uint2 zw = smem[0];
    f32x2 ze0 = __builtin_amdgcn_cvt_pk_f32_fp8(zw.x, false);
    f32x2 ze1 = __builtin_amdgcn_cvt_pk_f32_fp8(zw.x, true);
    f32x2 ze2 = __builtin_amdgcn_cvt_pk_f32_fp8(zw.y, false);
    f32x2 ze3 = __builtin_amdgcn_cvt_pk_f32_fp8(zw.y, true);
    float z[8] = {ze0.x, ze0.y, ze1.x, ze1.y, ze2.x, ze2.y, ze3.x, ze3.y};

    const char* sb = (const char*)smem;

#pragma unroll
    for (int it = 0; it < 2; ++it) {
        int o = obase + tid + it * 1024;
        // prefetch next batch
        uint4 n0 = q0, n1 = q1, n2 = q2, n3 = q3;
        if (it == 0) {
            int op = o + 1024; if (op >= oend) op = oend - 1;
            n0 = AQ[op];
            n1 = AQ[OUTN + op];
            n2 = AQ[2 * OUTN + op];
            n3 = AQ[3 * OUTN + op];
        }
        if (o < oend) {
            float a[8] = {0.f, 0.f, 0.f, 0.f, 0.f, 0.f, 0.f, 0.f};
#define DO_U32(u)                                                       \
            {                                                           \
                uint32_t off0 = (u & 0xFFFFu) << 2;                     \
                uint32_t off1 = (u >> 16) << 2;                         \
                uint2 v0 = *(const uint2*)(sb + off0);                  \
                uint2 v1 = *(const uint2*)(sb + off1);                  \
                f32x2 e;                                                \
                e = __builtin_amdgcn_cvt_pk_f32_fp8(v0.x, false);       \
                a[0] += e.x; a[1] += e.y;                               \
                e = __builtin_amdgcn_cvt_pk_f32_fp8(v0.x, true);        \
                a[2] += e.x; a[3] += e.y;                               \
                e = __builtin_amdgcn_cvt_pk_f32_fp8(v0.y, false);       \
                a[4] += e.x; a[5] += e.y;                               \
                e = __builtin_amdgcn_cvt_pk_f32_fp8(v0.y, true);        \
                a[6] += e.x; a[7] += e.y;                               \
                e = __builtin_amdgcn_cvt_pk_f32_fp8(v1.x, false);       \
                a[0] += e.x; a[1] += e.y;                               \
                e = __builtin_amdgcn_cvt_pk_f32_fp8(v1.x, true);        \
                a[2] += e.x; a[3] += e.y;                               \
                e = __builtin_amdgcn_cvt_pk_f32_fp8(v1.y, false);       \
                a[4] += e.x; a[5] += e.y;                               \
                e = __builtin_amdgcn_cvt_pk_f32_fp8(v1.y, true);        \
                a[6] += e.x; a[7] += e.y;                               \
            }
            DO_U32(q0.x) DO_U32(q0.y) DO_U32(q0.z) DO_U32(q0.w)
            DO_U32(q1.x) DO_U32(q1.y) DO_U32(q1.z) DO_U32(q1.w)
            DO_U32(q2.x) DO_U32(q2.y) DO_U32(q2.z) DO_U32(q2.w)
            DO_U32(q3.x) DO_U32(q3.y) DO_U32(q3.z) DO_U32(q3.w)
#undef DO_U32
            float2 sc = scale2[o];   // {invdeg/256, 32-deg}
#pragma unroll
            for (int cl = 0; cl < 8; ++cl) {
                float r = (a[cl] - sc.y * z[cl]) * sc.x;
                pooled[((size_t)(b * OUTC + c0 + cl)) * OUTN + o] = r;
            }
        }
        q0 = n0; q1 = n1; q2 = n2; q3 = n3;
    }
}

// ---------- kernel 3: y = W @ pooled + bias (in place over d_out) ----------
__global__ __launch_bounds__(256)
void out_kernel(float* io, const float* __restrict__ W_T,
                const float* __restrict__ bias) {
    __shared__ __align__(16) float sp[INC][128];
    __shared__ __align__(16) float sw[INC][OUTC];
    int obase = blockIdx.x * 128;
    int b     = blockIdx.y;

    const float* pb = io + (size_t)b * INC * OUTN;
    for (int idx = threadIdx.x; idx < INC * 32; idx += 256) {   // 2048 float4
        int c  = idx >> 5;
        int q  = idx & 31;
        int o4 = obase + q * 4;
        float4 v = (o4 < OUTN) ? *(const float4*)(pb + (size_t)c * OUTN + o4)
                               : make_float4(0.f, 0.f, 0.f, 0.f);
        *(float4*)(&sp[c][q * 4]) = v;
    }
    for (int idx = threadIdx.x; idx < (INC * OUTC) / 4; idx += 256) { // 1024 float4
        ((float4*)sw)[idx] = ((const float4*)W_T)[idx];
    }
    __syncthreads();

    int t   = threadIdx.x;
    int kt  = t >> 4;            // 0..15
    int ot0 = (t & 15) * 8;      // 0..120
    int k0  = kt * 4;

    float acc[4][8];
#pragma unroll
    for (int kk = 0; kk < 4; ++kk) {
#pragma unroll
        for (int jh = 0; jh < 2; ++jh) {
            int o4 = obase + ot0 + jh * 4;
            float4 bv = (o4 < OUTN)
                ? *(const float4*)(bias + (size_t)(k0 + kk) * OUTN + o4)
                : make_float4(0.f, 0.f, 0.f, 0.f);
            acc[kk][jh * 4 + 0] = bv.x;
            acc[kk][jh * 4 + 1] = bv.y;
            acc[kk][jh * 4 + 2] = bv.z;
            acc[kk][jh * 4 + 3] = bv.w;
        }
    }

#pragma unroll 4
    for (int c = 0; c < INC; ++c) {
        float4 w4  = *(const float4*)(&sw[c][k0]);
        float4 pa  = *(const float4*)(&sp[c][ot0]);
        float4 pb4 = *(const float4*)(&sp[c][ot0 + 4]);
        float p[8] = {pa.x, pa.y, pa.z, pa.w, pb4.x, pb4.y, pb4.z, pb4.w};
        float wv[4] = {w4.x, w4.y, w4.z, w4.w};
#pragma unroll
        for (int kk = 0; kk < 4; ++kk)
#pragma unroll
            for (int j = 0; j < 8; ++j)
                acc[kk][j] += wv[kk] * p[j];
    }

    int o0 = obase + ot0;
    if (o0 < OUTN) {    // OUTN % 8 == 0 -> whole 8 valid
#pragma unroll
        for (int kk = 0; kk < 4; ++kk) {
            float4 s0 = make_float4(acc[kk][0], acc[kk][1], acc[kk][2], acc[kk][3]);
            float4 s1 = make_float4(acc[kk][4], acc[kk][5], acc[kk][6], acc[kk][7]);
            float* dst = io + ((size_t)(b * OUTC + k0 + kk)) * OUTN + o0;
            *(float4*)(dst)     = s0;
            *(float4*)(dst + 4) = s1;
        }
    }
}

// ---------- launch ----------
extern "C" void kernel_launch(void* const* d_in, const int* in_sizes, int n_in,
                              void* d_out, int out_size, void* d_ws, size_t ws_size,
                              hipStream_t stream) {
    const float* x    = (const float*)d_in[0];
    const float* w    = (const float*)d_in[1];
    const float* ct_v = (const float*)d_in[2];
    const float* ct_g = (const float*)d_in[3];
    const float* bias = (const float*)d_in[4];
    const float* mask = (const float*)d_in[5];
    const int*   A    = (const int*)d_in[6];
    float* y = (float*)d_out;

    char* ws = (char*)d_ws;
    uint2*  xwi    = (uint2*)(ws);                    // 8*8*20000*8 = 10,240,000 B
    uint4*  AQ     = (uint4*)(ws + 10240000);         // 4*8000*16   =    512,000 B
    float2* scale2 = (float2*)(ws + 10752000);        // 8000*8      =     64,000 B
    float*  W_T    = (float*)(ws + 10816000);         // 64*64*4     =     16,384 B

    xw_kernel<<<dim3(40, 8, NB), 256, 0, stream>>>(x, w, xwi);
    prep_kernel<<<65, 128, 0, stream>>>(A, mask, ct_v, ct_g, AQ, scale2, W_T);
    gather_kernel<<<dim3(4, 8, NB), 1024, 0, stream>>>(xwi, AQ, scale2, y);
    out_kernel<<<dim3(63, NB), 256, 0, stream>>>(y, W_T, bias);
}